// Round 9
// baseline (462.999 us; speedup 1.0000x reference)
//
#include <hip/hip_runtime.h>
#include <hip/hip_bf16.h>

typedef __bf16 bf16_t;
typedef __bf16 bf16x8 __attribute__((ext_vector_type(8)));
typedef float f32x4 __attribute__((ext_vector_type(4)));
typedef float f32x8 __attribute__((ext_vector_type(8)));
typedef float f32x16 __attribute__((ext_vector_type(16)));
typedef unsigned int u32;

#define GAS __attribute__((address_space(1)))
#define LAS __attribute__((address_space(3)))

#define B_N 32
#define T_N 2048
#define C_N 256
#define F_N 1024
#define NSPLIT 16
#define TSUB 128
#define NCHUNK 32
#define CHBYTES 32768

// ---- inline-asm primitives: slot-disciplined LDS pipeline ----
#define DSR(dst, addr, IMM) \
  asm volatile("ds_read_b128 %0, %1 offset:" IMM : "=&v"(dst) : "v"(addr))
#define LGK(N) asm volatile("s_waitcnt lgkmcnt(" N ")")
#define MFA_A(acc, A, B) \
  asm volatile("v_mfma_f32_32x32x16_bf16 %0, %1, %2, %0" : "+a"(acc) : "v"(A), "v"(B))
#define MFA_V(acc, A, B) \
  asm volatile("v_mfma_f32_32x32x16_bf16 %0, %1, %2, %0" : "+v"(acc) : "v"(A), "v"(B))

// GEMM1 step: consume slot SL (W1 frag), feed both token tiles, prefetch next
#define G1STEP(SL, KS, IMMN) \
  LGK("3"); MFA_V(D1a, SL, hfrag[0][KS]); MFA_V(D1b, SL, hfrag[1][KS]); \
  DSR(SL, a_w1, IMMN)
#define G1TAIL(SL, KS, BQ, IMMB) \
  LGK("3"); MFA_V(D1a, SL, hfrag[0][KS]); MFA_V(D1b, SL, hfrag[1][KS]); \
  DSR(BQ, a_b1, IMMB)

// GEMM2 step: consume slot SL (W2 frag), both token tiles, prefetch next
#define G2STEP(SL, NB, AF0, AF1, IMMN) \
  LGK("3"); MFA_A(accO0[NB], AF0, SL); MFA_A(accO1[NB], AF1, SL); \
  DSR(SL, a_w2, IMMN)
#define G2TAIL(SL, NB, AF0, AF1, N) \
  LGK(N); MFA_A(accO0[NB], AF0, SL); MFA_A(accO1[NB], AF1, SL)

// ---------------- weight prep: build LDS-image layouts in ws ----------------
// W1 image per chunk ch (32 hidden rows): entry (kg 0..31, hl 0..31) 16B =
//   { bf16(W1[kg*8+j][ch*32+hl]) j=0..7 }  at  ch*32768 + kg*512 + hl*16
// W2 image per chunk: entry (G 0..3, cc 0..255) 16B at ch*32768 + 16384 + G*4096 + cc*16
//   element e = bf16(W2[ch*32 + perm(G,e)][cc]),  perm = (e&3) + 8*(2*(G>>1)+(e>>2)) + 4*(G&1)
__global__ __launch_bounds__(256) void k_prep(
    const float* __restrict__ W1, const float* __restrict__ W2,
    bf16_t* __restrict__ wsW) {
  int id = blockIdx.x * 256 + threadIdx.x;
  char* wb = (char*)wsW;
  if (id < 32768) {
    const int kg = id >> 10, h = id & 1023;
    const int ch = h >> 5, hl = h & 31;
    const float* src = W1 + (size_t)(kg << 3) * F_N + h;
    bf16x8 v;
#pragma unroll
    for (int j = 0; j < 8; ++j) v[j] = (bf16_t)src[(size_t)j * F_N];
    *(bf16x8*)(wb + (size_t)ch * CHBYTES + (kg << 9) + (hl << 4)) = v;
  } else {
    id -= 32768;
    const int Hg = id >> 8, cc = id & 255;
    const int ch = Hg >> 2, G = Hg & 3;
    bf16x8 v;
#pragma unroll
    for (int e = 0; e < 8; ++e) {
      const int hid = (ch << 5) + (e & 3) + ((((G >> 1) << 1) + (e >> 2)) << 3) + ((G & 1) << 2);
      v[e] = (bf16_t)W2[(size_t)hid * C_N + cc];
    }
    *(bf16x8*)(wb + (size_t)ch * CHBYTES + 16384 + (G << 12) + (cc << 4)) = v;
  }
}

// ---------------- stats pass 1 ----------------
__global__ __launch_bounds__(256) void k_stats_partial(
    const float* __restrict__ x, float* __restrict__ psum, float* __restrict__ psq) {
  const int blk = blockIdx.x;
  const int b = blk / NSPLIT, s = blk % NSPLIT;
  const int tid = threadIdx.x;
  const int c4 = (tid & 63) << 2;
  const int tg = tid >> 6;
  const float* xb = x + ((size_t)b * T_N + (size_t)s * TSUB) * C_N;
  f32x4 sum = {0.f, 0.f, 0.f, 0.f};
  f32x4 sq  = {0.f, 0.f, 0.f, 0.f};
#pragma unroll 4
  for (int i = 0; i < TSUB / 4; ++i) {
    const int t = tg + (i << 2);
    f32x4 v = *(const f32x4*)(xb + (size_t)t * C_N + c4);
    sum += v;
    sq += v * v;
  }
  __shared__ f32x4 ls[256];
  __shared__ f32x4 lq[256];
  ls[tid] = sum; lq[tid] = sq;
  __syncthreads();
  if (tid < 64) {
    f32x4 S = ls[tid] + ls[tid + 64] + ls[tid + 128] + ls[tid + 192];
    f32x4 Q = lq[tid] + lq[tid + 64] + lq[tid + 128] + lq[tid + 192];
    *(f32x4*)(psum + (size_t)blk * C_N + c4) = S;
    *(f32x4*)(psq  + (size_t)blk * C_N + c4) = Q;
  }
}

// ---------------- stats pass 2 (ddof=1) ----------------
__global__ __launch_bounds__(256) void k_stats_final(
    const float* __restrict__ psum, const float* __restrict__ psq,
    const float* __restrict__ gamma, const float* __restrict__ beta,
    float* __restrict__ As, float* __restrict__ Bs) {
  const int b = blockIdx.x, c = threadIdx.x;
  float S = 0.f, Q = 0.f;
#pragma unroll
  for (int s = 0; s < NSPLIT; ++s) {
    S += psum[(size_t)(b * NSPLIT + s) * C_N + c];
    Q += psq[(size_t)(b * NSPLIT + s) * C_N + c];
  }
  const float mu = S / (float)T_N;
  const float var = (Q - (float)T_N * mu * mu) / (float)(T_N - 1);
  const float a = rsqrtf(var + 1e-5f) * gamma[c];
  As[b * C_N + c] = a;
  Bs[b * C_N + c] = beta[c] - mu * a;
}

// ---------------- fused FFN: M=64/wave @ 1 wave/SIMD, both GEMMs slot-asm,
// every weight fragment read once feeds 2 MFMAs. 3-slot ring, vmcnt(8). ----------------
__global__ __launch_bounds__(256, 1) void k_ffn(
    const float* __restrict__ x, const float* __restrict__ As,
    const float* __restrict__ Bs, const float* __restrict__ b1,
    const float* __restrict__ b2, const bf16_t* __restrict__ wsW,
    float* __restrict__ out) {
  __shared__ __attribute__((aligned(128))) unsigned char lds[3 * CHBYTES + 4096];
  float* b1lds = (float*)(lds + 3 * CHBYTES);

  const int tid = threadIdx.x;            // 0..255, 4 waves
  const int lane = tid & 63;
  const int w = tid >> 6;
  const int l31 = lane & 31;
  const int g = lane >> 5;

  const int tok0 = blockIdx.x << 8;       // 256 tokens / block
  const int b = blockIdx.x >> 3;          // 8 blocks per batch row
  const int t0 = tok0 + (w << 6);         // this wave's 64 tokens (2 tiles of 32)

  const char* wsb = (const char*)wsW;

  // stage chunk 0 -> slot 0, chunk 1 -> slot 1 (8 x 16B per thread each)
#pragma unroll
  for (int j = 0; j < 8; ++j) {
    const int off = (j << 12) + (tid << 4);
    __builtin_amdgcn_global_load_lds((const GAS u32*)(wsb + off),
                                     (LAS u32*)(&lds[off]), 16, 0, 0);
  }
#pragma unroll
  for (int j = 0; j < 8; ++j) {
    const int off = (j << 12) + (tid << 4);
    __builtin_amdgcn_global_load_lds((const GAS u32*)(wsb + CHBYTES + off),
                                     (LAS u32*)(&lds[CHBYTES + off]), 16, 0, 0);
  }

  // b1 -> LDS (1024 f32, 4 per thread)
  *(f32x4*)(b1lds + (tid << 2)) = *(const f32x4*)(b1 + (tid << 2));

  // prologue: normalized h fragments for both token tiles (128 VGPR)
  bf16x8 hfrag[2][16];
  {
    const float* ar = As + b * C_N;
    const float* br = Bs + b * C_N;
#pragma unroll
    for (int ti = 0; ti < 2; ++ti) {
      const float* xrow = x + (size_t)(t0 + (ti << 5) + l31) * C_N;
#pragma unroll
      for (int ks = 0; ks < 16; ++ks) {
        const int c0 = (ks << 4) + (g << 3);
        f32x8 xv = *(const f32x8*)(xrow + c0);
        f32x8 av = *(const f32x8*)(ar + c0);
        f32x8 bv = *(const f32x8*)(br + c0);
        f32x8 hv = xv * av + bv;
#pragma unroll
        for (int e = 0; e < 8; ++e) hfrag[ti][ks][e] = (bf16_t)hv[e];
      }
    }
  }

  f32x16 accO0[8], accO1[8];
#pragma unroll
  for (int nb = 0; nb < 8; ++nb)
#pragma unroll
    for (int e = 0; e < 16; ++e) { accO0[nb][e] = 0.f; accO1[nb][e] = 0.f; }

  const unsigned b1u = (unsigned)(size_t)b1lds;

  __syncthreads();   // chunks 0/1 staged, b1 visible; all counters drained

  const unsigned char* bufA = lds;                 // compute (ch)
  const unsigned char* bufB = lds + CHBYTES;       // ready (ch+1)
  unsigned char* bufC = lds + 2 * CHBYTES;         // stage target (ch+2)
  const char* gnext = wsb + 2 * (size_t)CHBYTES;

#pragma unroll 1
  for (int ch = 0; ch < NCHUNK; ++ch) {
    // issue stage of ch+2 (8 loads/thread, vmcnt domain; in flight across barrier)
    if (ch + 2 < NCHUNK) {
#pragma unroll
      for (int j = 0; j < 8; ++j) {
        const int off = (j << 12) + (tid << 4);
        __builtin_amdgcn_global_load_lds((const GAS u32*)(gnext + off),
                                         (LAS u32*)(bufC + off), 16, 0, 0);
      }
      gnext += CHBYTES;
    }

    const unsigned lbase = (unsigned)(size_t)bufA;
    const unsigned a_w1 = lbase + (g << 9) + (l31 << 4);
    const unsigned a_w2 = lbase + 16384 + (g << 12) + (l31 << 4);
    const unsigned a_b1 = b1u + (ch << 7) + (g << 4);

    // zero D1 BEFORE the fence (rule: no VALU may sink into the asm region)
    f32x16 D1a, D1b;
#pragma unroll
    for (int e = 0; e < 16; ++e) { D1a[e] = 0.f; D1b[e] = 0.f; }
    f32x4 b1q0, b1q1, b1q2, b1q3;

    LGK("0");                               // lgkm baseline = 0
    __builtin_amdgcn_sched_barrier(0);

    // ---- GEMM1 (asm): 16 W1 frags, each feeds 2 MFMAs; 4-slot, 4-ahead ----
    {
      bf16x8 s0, s1, s2, s3;
      DSR(s0, a_w1, "0"); DSR(s1, a_w1, "1024");
      DSR(s2, a_w1, "2048"); DSR(s3, a_w1, "3072");
      G1STEP(s0, 0, "4096");  G1STEP(s1, 1, "5120");
      G1STEP(s2, 2, "6144");  G1STEP(s3, 3, "7168");
      G1STEP(s0, 4, "8192");  G1STEP(s1, 5, "9216");
      G1STEP(s2, 6, "10240"); G1STEP(s3, 7, "11264");
      G1STEP(s0, 8, "12288"); G1STEP(s1, 9, "13312");
      G1STEP(s2, 10, "14336"); G1STEP(s3, 11, "15360");
      G1TAIL(s0, 12, b1q0, "0");  G1TAIL(s1, 13, b1q1, "32");
      G1TAIL(s2, 14, b1q2, "64"); G1TAIL(s3, 15, b1q3, "96");
      LGK("0");
      asm volatile("s_nop 7\ns_nop 7\ns_nop 2");   // MFMA(D1) -> VALU read spacing
      __builtin_amdgcn_sched_barrier(0);

      // ---- bias + ReLU + cast (C++ VALU): reg r holds hid=(r&3)+8*(r>>2)+4g ----
      bf16x8 af0, af0b, af1, af1b;
#pragma unroll
      for (int r = 0; r < 16; ++r) {
        const float bb = (r < 4 ? b1q0 : r < 8 ? b1q1 : r < 12 ? b1q2 : b1q3)[r & 3];
        float v0 = D1a[r] + bb;
        float v1 = D1b[r] + bb;
        v0 = v0 > 0.f ? v0 : 0.f;
        v1 = v1 > 0.f ? v1 : 0.f;
        if (r < 8) { af0[r] = (bf16_t)v0; af1[r] = (bf16_t)v1; }
        else       { af0b[r - 8] = (bf16_t)v0; af1b[r - 8] = (bf16_t)v1; }
      }
      __builtin_amdgcn_sched_barrier(0);
      asm volatile("s_nop 4");                     // VALU(af) -> MFMA srcA spacing

      // ---- GEMM2 (asm): 16 W2 frags, each feeds 2 MFMAs; 4-slot, 4-ahead ----
      DSR(s0, a_w2, "0"); DSR(s1, a_w2, "512");
      DSR(s2, a_w2, "1024"); DSR(s3, a_w2, "1536");
      G2STEP(s0, 0, af0, af1, "2048");   G2STEP(s1, 1, af0, af1, "2560");
      G2STEP(s2, 2, af0, af1, "3072");   G2STEP(s3, 3, af0, af1, "3584");
      G2STEP(s0, 4, af0, af1, "8192");   G2STEP(s1, 5, af0, af1, "8704");
      G2STEP(s2, 6, af0, af1, "9216");   G2STEP(s3, 7, af0, af1, "9728");
      G2STEP(s0, 0, af0b, af1b, "10240"); G2STEP(s1, 1, af0b, af1b, "10752");
      G2STEP(s2, 2, af0b, af1b, "11264"); G2STEP(s3, 3, af0b, af1b, "11776");
      G2TAIL(s0, 4, af0b, af1b, "3");
      G2TAIL(s1, 5, af0b, af1b, "2");
      G2TAIL(s2, 6, af0b, af1b, "1");
      G2TAIL(s3, 7, af0b, af1b, "0");
      __builtin_amdgcn_sched_barrier(0);
    }

    // counted wait: ch+1's 8 stage loads landed; ch+2's 8 stay in flight.
    if (ch + 2 < NCHUNK) {
      asm volatile("s_waitcnt vmcnt(8)\n\ts_barrier" ::: "memory");
    } else if (ch + 1 < NCHUNK) {
      asm volatile("s_waitcnt vmcnt(0)\n\ts_barrier" ::: "memory");
    }

    const unsigned char* t = bufA; bufA = bufB; bufB = bufC; bufC = (unsigned char*)t;
  }

  // asm MFMA (AGPR write) -> VALU/accvgpr_read hazard spacing
  asm volatile("s_nop 7\ns_nop 7\ns_nop 2");

  // epilogue: out = accO + b2 + x  (token = t0 + ti*32 + 4g + rr + 8q, col = nb*32 + l31)
#pragma unroll
  for (int ti = 0; ti < 2; ++ti) {
    const float* xbase = x + (size_t)(t0 + (ti << 5) + (g << 2)) * C_N;
    float* obase = out + (size_t)(t0 + (ti << 5) + (g << 2)) * C_N;
#pragma unroll
    for (int nb = 0; nb < 8; ++nb) {
      const int c = (nb << 5) + l31;
      const float b2v = b2[c];
#pragma unroll
      for (int q = 0; q < 4; ++q) {
#pragma unroll
        for (int rr = 0; rr < 4; ++rr) {
          const size_t idx = (size_t)((q << 3) + rr) * C_N + c;
          const f32x16& a = ti ? accO1[nb] : accO0[nb];
          obase[idx] = a[(q << 2) + rr] + b2v + xbase[idx];
        }
      }
    }
  }
}

extern "C" void kernel_launch(void* const* d_in, const int* in_sizes, int n_in,
                              void* d_out, int out_size, void* d_ws, size_t ws_size,
                              hipStream_t stream) {
  const float* x     = (const float*)d_in[0];
  const float* gamma = (const float*)d_in[1];
  const float* beta  = (const float*)d_in[2];
  const float* W1    = (const float*)d_in[3];
  const float* b1    = (const float*)d_in[4];
  const float* W2    = (const float*)d_in[5];
  const float* b2    = (const float*)d_in[6];
  float* out = (float*)d_out;

  char* ws = (char*)d_ws;
  bf16_t* wsW  = (bf16_t*)ws;                           // 1 MB
  float* psum  = (float*)(ws + (1024 << 10));           // 512 KB
  float* psq   = (float*)(ws + (1536 << 10));           // 512 KB
  float* As    = (float*)(ws + (2048 << 10));           // 32 KB
  float* Bs    = (float*)(ws + (2048 << 10) + (32 << 10));

  k_prep<<<256, 256, 0, stream>>>(W1, W2, wsW);
  k_stats_partial<<<B_N * NSPLIT, 256, 0, stream>>>(x, psum, psq);
  k_stats_final<<<B_N, 256, 0, stream>>>(psum, psq, gamma, beta, As, Bs);
  k_ffn<<<256, 256, 0, stream>>>(x, As, Bs, b1, b2, wsW, out);
}

// Round 10
// 105.813 us; speedup vs baseline: 4.3756x; 4.3756x over previous
//
#include <hip/hip_runtime.h>
#include <hip/hip_bf16.h>

typedef __bf16 bf16_t;
typedef __bf16 bf16x8 __attribute__((ext_vector_type(8)));
typedef float f32x4 __attribute__((ext_vector_type(4)));
typedef float f32x8 __attribute__((ext_vector_type(8)));
typedef float f32x16 __attribute__((ext_vector_type(16)));
typedef unsigned int u32;

#define GAS __attribute__((address_space(1)))
#define LAS __attribute__((address_space(3)))

#define B_N 32
#define T_N 2048
#define C_N 256
#define F_N 1024
#define NSPLIT 16
#define TSUB 128
#define NCHUNK 32
#define CHB 33792               // 16KB W1 + 1KB bias-kg-pair + 16KB W2
#define NITER 16                // 2 chunks per barrier interval

#define MF(A, B, C) __builtin_amdgcn_mfma_f32_32x32x16_bf16((A), (B), (C), 0, 0, 0)

// ---------------- weight prep: per-chunk images {W1 | bias-K-ext | W2} ----------------
// W1: entry (kg 0..31, hl 0..31) 16B = { bf16(W1[kg*8+j][ch*32+hl]) } at kg*512 + hl*16
// bias K-ext: kg-pair at 16384: g=0 entry hl -> {bf16(b1[ch*32+hl]),0..}; g=1 -> zeros
// W2: entry (G 0..3, cc 0..255) at 17408 + G*4096 + cc*16, elem e = bf16(W2[ch*32+perm(G,e)][cc]),
//     perm = (e&3) + 8*(2*(G>>1)+(e>>2)) + 4*(G&1)   (matches swapped-GEMM1 D-reg order)
__global__ __launch_bounds__(256) void k_prep(
    const float* __restrict__ W1, const float* __restrict__ b1,
    const float* __restrict__ W2, bf16_t* __restrict__ wsW) {
  const int id = blockIdx.x * 256 + threadIdx.x;      // 0 .. 67583
  const int ch = id / 2112;
  const int r = id % 2112;
  char* base = (char*)wsW + (size_t)ch * CHB;
  if (r < 1024) {
    const int kg = r >> 5, hl = r & 31;
    const int h = (ch << 5) + hl;
    const float* src = W1 + (size_t)(kg << 3) * F_N + h;
    bf16x8 v;
#pragma unroll
    for (int j = 0; j < 8; ++j) v[j] = (bf16_t)src[(size_t)j * F_N];
    *(bf16x8*)(base + (kg << 9) + (hl << 4)) = v;
  } else if (r < 1088) {
    const int gg = (r - 1024) >> 5, hl = (r - 1024) & 31;
    bf16x8 v;
#pragma unroll
    for (int e = 0; e < 8; ++e) v[e] = (bf16_t)0.f;
    if (gg == 0) v[0] = (bf16_t)b1[(ch << 5) + hl];
    *(bf16x8*)(base + 16384 + (gg << 9) + (hl << 4)) = v;
  } else {
    const int idx = r - 1088;
    const int G = idx >> 8, cc = idx & 255;
    bf16x8 v;
#pragma unroll
    for (int e = 0; e < 8; ++e) {
      const int hid = (ch << 5) + (e & 3) + ((((G >> 1) << 1) + (e >> 2)) << 3) + ((G & 1) << 2);
      v[e] = (bf16_t)W2[(size_t)hid * C_N + cc];
    }
    *(bf16x8*)(base + 17408 + (G << 12) + (cc << 4)) = v;
  }
}

// ---------------- stats pass 1: partial sum / sumsq over a T-slice ----------------
__global__ __launch_bounds__(256) void k_stats_partial(
    const float* __restrict__ x, float* __restrict__ psum, float* __restrict__ psq) {
  const int blk = blockIdx.x;
  const int b = blk / NSPLIT, s = blk % NSPLIT;
  const int tid = threadIdx.x;
  const int c4 = (tid & 63) << 2;
  const int tg = tid >> 6;
  const float* xb = x + ((size_t)b * T_N + (size_t)s * TSUB) * C_N;
  f32x4 sum = {0.f, 0.f, 0.f, 0.f};
  f32x4 sq  = {0.f, 0.f, 0.f, 0.f};
#pragma unroll 4
  for (int i = 0; i < TSUB / 4; ++i) {
    const int t = tg + (i << 2);
    f32x4 v = *(const f32x4*)(xb + (size_t)t * C_N + c4);
    sum += v;
    sq += v * v;
  }
  __shared__ f32x4 ls[256];
  __shared__ f32x4 lq[256];
  ls[tid] = sum; lq[tid] = sq;
  __syncthreads();
  if (tid < 64) {
    f32x4 S = ls[tid] + ls[tid + 64] + ls[tid + 128] + ls[tid + 192];
    f32x4 Q = lq[tid] + lq[tid + 64] + lq[tid + 128] + lq[tid + 192];
    *(f32x4*)(psum + (size_t)blk * C_N + c4) = S;
    *(f32x4*)(psq  + (size_t)blk * C_N + c4) = Q;
  }
}

// ---------------- stats pass 2: fused scale/shift (ddof=1) ----------------
__global__ __launch_bounds__(256) void k_stats_final(
    const float* __restrict__ psum, const float* __restrict__ psq,
    const float* __restrict__ gamma, const float* __restrict__ beta,
    float* __restrict__ As, float* __restrict__ Bs) {
  const int b = blockIdx.x, c = threadIdx.x;
  float S = 0.f, Q = 0.f;
#pragma unroll
  for (int s = 0; s < NSPLIT; ++s) {
    S += psum[(size_t)(b * NSPLIT + s) * C_N + c];
    Q += psq[(size_t)(b * NSPLIT + s) * C_N + c];
  }
  const float mu = S / (float)T_N;
  const float var = (Q - (float)T_N * mu * mu) / (float)(T_N - 1);
  const float a = rsqrtf(var + 1e-5f) * gamma[c];
  As[b * C_N + c] = a;
  Bs[b * C_N + c] = beta[c] - mu * a;
}

// GEMM1 (swapped, bias folded as 17th MFMA): 4-slot software-pipelined ds reads.
// D-reg r holds hid = (r&3)+8*(r>>2)+4g for token col l31. AF = relu(D1), bf16.
#define GEMM1(CB, AF) { \
  const unsigned char* wb_ = (CB) + (g << 9) + (l31 << 4); \
  bf16x8 p0 = *(const bf16x8*)((CB) + 16384 + (g << 9) + (l31 << 4)); \
  bf16x8 p1 = *(const bf16x8*)(wb_); \
  bf16x8 p2 = *(const bf16x8*)(wb_ + 1024); \
  bf16x8 p3 = *(const bf16x8*)(wb_ + 2048); \
  f32x16 D1; \
  _Pragma("unroll") for (int e_ = 0; e_ < 16; ++e_) D1[e_] = 0.f; \
  D1 = MF(p0, hext, D1);      p0 = *(const bf16x8*)(wb_ + 3072); \
  D1 = MF(p1, hfrag[0], D1);  p1 = *(const bf16x8*)(wb_ + 4096); \
  D1 = MF(p2, hfrag[1], D1);  p2 = *(const bf16x8*)(wb_ + 5120); \
  D1 = MF(p3, hfrag[2], D1);  p3 = *(const bf16x8*)(wb_ + 6144); \
  D1 = MF(p0, hfrag[3], D1);  p0 = *(const bf16x8*)(wb_ + 7168); \
  D1 = MF(p1, hfrag[4], D1);  p1 = *(const bf16x8*)(wb_ + 8192); \
  D1 = MF(p2, hfrag[5], D1);  p2 = *(const bf16x8*)(wb_ + 9216); \
  D1 = MF(p3, hfrag[6], D1);  p3 = *(const bf16x8*)(wb_ + 10240); \
  D1 = MF(p0, hfrag[7], D1);  p0 = *(const bf16x8*)(wb_ + 11264); \
  D1 = MF(p1, hfrag[8], D1);  p1 = *(const bf16x8*)(wb_ + 12288); \
  D1 = MF(p2, hfrag[9], D1);  p2 = *(const bf16x8*)(wb_ + 13312); \
  D1 = MF(p3, hfrag[10], D1); p3 = *(const bf16x8*)(wb_ + 14336); \
  D1 = MF(p0, hfrag[11], D1); p0 = *(const bf16x8*)(wb_ + 15360); \
  D1 = MF(p1, hfrag[12], D1); \
  D1 = MF(p2, hfrag[13], D1); \
  D1 = MF(p3, hfrag[14], D1); \
  D1 = MF(p0, hfrag[15], D1); \
  _Pragma("unroll") for (int r_ = 0; r_ < 16; ++r_) { \
    float v_ = D1[r_]; \
    v_ = v_ > 0.f ? v_ : 0.f; \
    AF[r_ >> 3][r_ & 7] = (bf16_t)v_; \
  } \
}

// GEMM2: 8 independent acc chains, 4-slot pipelined reads (16 frags).
#define GEMM2(CB, AF) { \
  const unsigned char* w2_ = (CB) + 17408 + (g << 12) + (l31 << 4); \
  bf16x8 q0 = *(const bf16x8*)(w2_); \
  bf16x8 q1 = *(const bf16x8*)(w2_ + 512); \
  bf16x8 q2 = *(const bf16x8*)(w2_ + 1024); \
  bf16x8 q3 = *(const bf16x8*)(w2_ + 1536); \
  accO[0] = MF(AF[0], q0, accO[0]); q0 = *(const bf16x8*)(w2_ + 2048); \
  accO[1] = MF(AF[0], q1, accO[1]); q1 = *(const bf16x8*)(w2_ + 2560); \
  accO[2] = MF(AF[0], q2, accO[2]); q2 = *(const bf16x8*)(w2_ + 3072); \
  accO[3] = MF(AF[0], q3, accO[3]); q3 = *(const bf16x8*)(w2_ + 3584); \
  accO[4] = MF(AF[0], q0, accO[4]); q0 = *(const bf16x8*)(w2_ + 8192); \
  accO[5] = MF(AF[0], q1, accO[5]); q1 = *(const bf16x8*)(w2_ + 8704); \
  accO[6] = MF(AF[0], q2, accO[6]); q2 = *(const bf16x8*)(w2_ + 9216); \
  accO[7] = MF(AF[0], q3, accO[7]); q3 = *(const bf16x8*)(w2_ + 9728); \
  accO[0] = MF(AF[1], q0, accO[0]); q0 = *(const bf16x8*)(w2_ + 10240); \
  accO[1] = MF(AF[1], q1, accO[1]); q1 = *(const bf16x8*)(w2_ + 10752); \
  accO[2] = MF(AF[1], q2, accO[2]); q2 = *(const bf16x8*)(w2_ + 11264); \
  accO[3] = MF(AF[1], q3, accO[3]); q3 = *(const bf16x8*)(w2_ + 11776); \
  accO[4] = MF(AF[1], q0, accO[4]); \
  accO[5] = MF(AF[1], q1, accO[5]); \
  accO[6] = MF(AF[1], q2, accO[6]); \
  accO[7] = MF(AF[1], q3, accO[7]); \
}

// stage one chunk-pair (67584 B) with 512 threads: 8 full 16B rounds + 2KB tail
#define STAGE(GSRC, LDST) { \
  _Pragma("unroll") for (int j_ = 0; j_ < 8; ++j_) { \
    const int off_ = (j_ << 13) + (tid << 4); \
    __builtin_amdgcn_global_load_lds((const GAS u32*)((GSRC) + off_), \
                                     (LAS u32*)((LDST) + off_), 16, 0, 0); \
  } \
  if (tid < 128) { \
    const int off_ = 65536 + (tid << 4); \
    __builtin_amdgcn_global_load_lds((const GAS u32*)((GSRC) + off_), \
                                     (LAS u32*)((LDST) + off_), 16, 0, 0); \
  } \
}

// ---------------- fused FFN: M=32/wave @ (512,2) proven envelope,
// bias-folded GEMM1, explicit 4-slot read pipelining, 2 chunks/barrier ----------------
__global__ __launch_bounds__(512, 2) void k_ffn(
    const float* __restrict__ x, const float* __restrict__ As,
    const float* __restrict__ Bs, const float* __restrict__ b2,
    const bf16_t* __restrict__ wsW, float* __restrict__ out) {
  __shared__ __attribute__((aligned(128))) unsigned char lds[2 * 2 * CHB];  // 132KB

  const int tid = threadIdx.x;            // 0..511, 8 waves
  const int lane = tid & 63;
  const int w = tid >> 6;
  const int l31 = lane & 31;
  const int g = lane >> 5;

  const int tok0 = blockIdx.x << 8;       // 256 tokens / block
  const int b = blockIdx.x >> 3;          // 8 blocks per batch row
  const int t0 = tok0 + (w << 5);         // this wave's 32 tokens

  const char* wsb = (const char*)wsW;

  // stage pair 0 into buffer 0
  STAGE(wsb, &lds[0]);

  // constant B-frag for the bias K-extension: B[tok][kext]=1 at kext=0 (g=0 lanes)
  bf16x8 hext;
#pragma unroll
  for (int e = 0; e < 8; ++e) hext[e] = (bf16_t)0.f;
  if (g == 0) hext[0] = (bf16_t)1.0f;

  // prologue: normalized h fragments (64 VGPR)
  bf16x8 hfrag[16];
  {
    const float* ar = As + b * C_N;
    const float* br = Bs + b * C_N;
    const float* xrow = x + (size_t)(t0 + l31) * C_N;
#pragma unroll
    for (int ks = 0; ks < 16; ++ks) {
      const int c0 = (ks << 4) + (g << 3);
      f32x8 xv = *(const f32x8*)(xrow + c0);
      f32x8 av = *(const f32x8*)(ar + c0);
      f32x8 bv = *(const f32x8*)(br + c0);
      f32x8 hv = xv * av + bv;
#pragma unroll
      for (int e = 0; e < 8; ++e) hfrag[ks][e] = (bf16_t)hv[e];
    }
  }

  f32x16 accO[8];
#pragma unroll
  for (int nb = 0; nb < 8; ++nb)
#pragma unroll
    for (int e = 0; e < 16; ++e) accO[nb][e] = 0.f;

  __syncthreads();   // pair 0 staged

#pragma unroll 1
  for (int it = 0; it < NITER; ++it) {
    const unsigned char* buf = &lds[(it & 1) * (2 * CHB)];

    // stage next pair into the other buffer; lands well before next barrier
    if (it + 1 < NITER) {
      const char* gsrc = wsb + (size_t)(it + 1) * (2 * CHB);
      unsigned char* ldst = &lds[((it + 1) & 1) * (2 * CHB)];
      STAGE(gsrc, ldst);
    }

    bf16x8 af0[2], af1[2];
    // chunk c0 = 2it
    GEMM1(buf, af0);
    GEMM2(buf, af0);
    // chunk c1 = 2it+1 (G2(c0)'s independent chains border G1(c1)'s serial chain)
    GEMM1(buf + CHB, af1);
    GEMM2(buf + CHB, af1);

    if (it + 1 < NITER) __syncthreads();
  }

  // epilogue: out = accO + b2 + x   (token = t0 + 4g + rr + 8q, col = nb*32 + l31)
  {
    const float* xbase = x + (size_t)(t0 + (g << 2)) * C_N;
    float* obase = out + (size_t)(t0 + (g << 2)) * C_N;
#pragma unroll
    for (int nb = 0; nb < 8; ++nb) {
      const int c = (nb << 5) + l31;
      const float b2v = b2[c];
#pragma unroll
      for (int q = 0; q < 4; ++q) {
#pragma unroll
        for (int rr = 0; rr < 4; ++rr) {
          const size_t idx = (size_t)((q << 3) + rr) * C_N + c;
          obase[idx] = accO[nb][(q << 2) + rr] + b2v + xbase[idx];
        }
      }
    }
  }
}

extern "C" void kernel_launch(void* const* d_in, const int* in_sizes, int n_in,
                              void* d_out, int out_size, void* d_ws, size_t ws_size,
                              hipStream_t stream) {
  const float* x     = (const float*)d_in[0];
  const float* gamma = (const float*)d_in[1];
  const float* beta  = (const float*)d_in[2];
  const float* W1    = (const float*)d_in[3];
  const float* b1    = (const float*)d_in[4];
  const float* W2    = (const float*)d_in[5];
  const float* b2    = (const float*)d_in[6];
  float* out = (float*)d_out;

  char* ws = (char*)d_ws;
  bf16_t* wsW  = (bf16_t*)ws;                           // 32 x 33792 = 1.03 MB
  float* psum  = (float*)(ws + (1088 << 10));           // 512 KB
  float* psq   = (float*)(ws + (1600 << 10));           // 512 KB
  float* As    = (float*)(ws + (2112 << 10));           // 32 KB
  float* Bs    = (float*)(ws + (2112 << 10) + (32 << 10));

  k_prep<<<264, 256, 0, stream>>>(W1, b1, W2, wsW);
  k_stats_partial<<<B_N * NSPLIT, 256, 0, stream>>>(x, psum, psq);
  k_stats_final<<<B_N, 256, 0, stream>>>(psum, psq, gamma, beta, As, Bs);
  k_ffn<<<256, 512, 0, stream>>>(x, As, Bs, b2, wsW, out);
}